// Round 11
// baseline (396.591 us; speedup 1.0000x reference)
//
#include <hip/hip_runtime.h>

typedef unsigned short ushort_t;
typedef __attribute__((ext_vector_type(8))) short short8;
typedef __attribute__((ext_vector_type(4))) float f32x4;
typedef __attribute__((ext_vector_type(4))) unsigned short u16x4;

#define B_ 4
#define L_ 1024
#define C_ 768
#define N_ 16
#define DR_ 48
#define HW_ 32
#define M_ (B_*L_)   // 4096 rows
#define SEG_ 64      // scan segment length
#define NSEG_ 16     // L_/SEG_

// Workspace layout (byte offsets), total 59,252,992 B:
//   0        IDX   (2*1024 int)
//   8192     FLAG
//   8448     XN region: XN -> DTC -> {SP,SQ bf16} -> HBUF
//   6299904  U region: U -> DT -> {fus_w1^T, fus_w2^T}
//   18882816 Z region: Z -> FUSED
//   31465728 UC region: in_w^T -> UC
//   44048640 DBL 2*M*80 f32
//   46670080 Y 2*M*C u16
// d_out doubles as scratch for {xproj^T, dtp^T, out_w^T} until S7 (dead til S9).

__device__ __forceinline__ float bf2f(ushort_t u) {
  union { unsigned int i; float f; } v; v.i = ((unsigned int)u) << 16; return v.f;
}
__device__ __forceinline__ ushort_t f2bf(float f) {
  union { float f; unsigned int i; } v; v.f = f;
  unsigned int x = v.i;
  return (ushort_t)((x + 0x7fffu + ((x >> 16) & 1u)) >> 16);
}
__device__ __forceinline__ float ldf(const void* p, size_t i, int bf) {
  return bf ? bf2f(((const ushort_t*)p)[i]) : ((const float*)p)[i];
}
// bf16-vs-fp32 detect on x's first 256 words. Wave-parallel: each of 64 lanes
// checks 4 consecutive u16 (one coalesced 8B load), then one ballot.
// Must be called with all 64 lanes of the wave active.
__device__ __forceinline__ int detect_bf(const void* x) {
  const ushort_t* u = (const ushort_t*)x;
  int lane = threadIdx.x & 63;
  const ushort_t* p = u + lane * 4;
  int bad = 0;
  #pragma unroll
  for (int i = 0; i < 4; ++i) {
    int e = (p[i] >> 7) & 0xFF;
    bad |= (e < 90 || e > 141);
  }
  return (__ballot(bad) == 0ull) ? 1 : 0;
}
// async global->LDS, 16 B per lane; lds dest = wave-uniform base + lane*16
__device__ __forceinline__ void gload_lds16(const void* g, void* lds) {
  __builtin_amdgcn_global_load_lds(
      (const __attribute__((address_space(1))) unsigned int*)g,
      (__attribute__((address_space(3))) unsigned int*)lds, 16, 0, 0);
}

// ---------------------------------------------------------------- prep kernel
// One dispatch: blocks [0,oT) weight transposes, [oT,oT+4096) layernorm rows,
// block oT+4096 spiral-idx + FLAG write. All independent.
struct TJ {
  const void* src[8]; ushort_t* dst[8];
  int R[8], Cc[8], RD[8], ldD[8];
  int off[9]; int njobs;
};

__global__ __launch_bounds__(256) void prep_k(
    TJ tj, const void* __restrict__ x, const void* __restrict__ nw,
    const void* __restrict__ nb, ushort_t* __restrict__ xn,
    int* idx_cw, int* idx_ccw, int* flag)
{
  const int oT = tj.off[tj.njobs];
  int bid = blockIdx.x;
  // one wave-parallel detect per block, all lanes active (uniform path)
  const int inbf = detect_bf(x);

  if (bid < oT) {                       // ---- transpose job
    int j = 0;
    while (bid >= tj.off[j+1]) ++j;
    const void* src = tj.src[j];
    ushort_t* dst = tj.dst[j];
    const int R = tj.R[j], Cc = tj.Cc[j], RD = tj.RD[j], ldD = tj.ldD[j];
    int cb_span = (Cc > RD ? Cc : RD);
    int txt = (cb_span + 31) >> 5;
    int t = bid - tj.off[j];
    int bx = (t % txt) * 32;
    int by = (t / txt) * 32;
    __shared__ ushort_t tile[32][33];
    int tx = threadIdx.x & 31, ty = threadIdx.x >> 5;
    #pragma unroll
    for (int i = 0; i < 4; ++i) {
      int r = by + ty + i*8, c = bx + tx;
      ushort_t v = 0;
      if (r < R && c < Cc) v = f2bf(ldf(src, (size_t)r * Cc + c, inbf));
      tile[ty + i*8][tx] = v;
    }
    __syncthreads();
    #pragma unroll
    for (int i = 0; i < 4; ++i) {
      int dr = bx + ty + i*8, dc = by + tx;
      if (dr < RD && dc < ldD)
        dst[(size_t)dr * ldD + dc] = tile[tx][ty + i*8];
    }
    return;
  }
  bid -= oT;
  if (bid < M_) {                       // ---- layernorm row
    int tid = threadIdx.x;
    size_t o0 = (size_t)bid * C_;
    float v0 = ldf(x, o0 + tid,       inbf);
    float v1 = ldf(x, o0 + tid + 256, inbf);
    float v2 = ldf(x, o0 + tid + 512, inbf);
    float s = v0 + v1 + v2, s2 = v0*v0 + v1*v1 + v2*v2;
    for (int o = 32; o > 0; o >>= 1) { s += __shfl_down(s, o); s2 += __shfl_down(s2, o); }
    __shared__ float ss[4], ss2[4];
    if ((tid & 63) == 0) { ss[tid >> 6] = s; ss2[tid >> 6] = s2; }
    __syncthreads();
    s  = ss[0] + ss[1] + ss[2] + ss[3];
    s2 = ss2[0] + ss2[1] + ss2[2] + ss2[3];
    float mean = s * (1.f / C_);
    float var  = s2 * (1.f / C_) - mean * mean;
    float inv  = rsqrtf(var + 1e-6f);
    xn[o0 + tid]       = f2bf((v0 - mean) * inv * ldf(nw, tid,     inbf) + ldf(nb, tid,     inbf));
    xn[o0 + tid + 256] = f2bf((v1 - mean) * inv * ldf(nw, tid+256, inbf) + ldf(nb, tid+256, inbf));
    xn[o0 + tid + 512] = f2bf((v2 - mean) * inv * ldf(nw, tid+512, inbf) + ldf(nb, tid+512, inbf));
    return;
  }
  // ---- setup block: PARALLEL analytic spiral-index generation.
  // Ring r of the WxW spiral starts at offset S_r = 4r(W-r); ring side s=W-2r;
  // within-ring position q maps closed-form to (i,j) for each of the 4 legs.
  {
    int tid = threadIdx.x;
    #pragma unroll
    for (int k = 0; k < 4; ++k) {
      int p = tid * 4 + k;                      // spiral position, 0..1023
      int r = 0;
      while (r < (HW_/2 - 1) && p >= 4*(r+1)*(HW_-(r+1))) ++r;
      int q = p - 4*r*(HW_-r);
      int s = HW_ - 2*r;
      int hi = HW_ - 1 - r;
      int icw, jcw, iccw, jccw;
      if (q < s)              { icw = r;                  jcw = r + q; }
      else if (q < 2*s-1)     { icw = r + 1 + (q - s);    jcw = hi; }
      else if (q < 3*s-2)     { icw = hi;                 jcw = hi - 1 - (q - (2*s-1)); }
      else                    { icw = hi - 1 - (q - (3*s-2)); jcw = r; }
      if (q < s)              { iccw = r;                 jccw = hi - q; }
      else if (q < 2*s-1)     { iccw = r + 1 + (q - s);   jccw = r; }
      else if (q < 3*s-2)     { iccw = hi;                jccw = r + 1 + (q - (2*s-1)); }
      else                    { iccw = hi - 1 - (q - (3*s-2)); jccw = hi; }
      idx_cw[p]  = icw  * HW_ + jcw;
      idx_ccw[p] = iccw * HW_ + jccw;
    }
    if (tid == 0) *flag = inbf;
  }
}

// ---------------------------------------------------------------- batched transpose
__global__ __launch_bounds__(256) void tbatch_k(TJ tj, const int* __restrict__ flagp) {
  const int inbf = *flagp;
  int bid = blockIdx.x;
  int j = 0;
  while (bid >= tj.off[j+1]) ++j;
  const void* src = tj.src[j];
  ushort_t* dst = tj.dst[j];
  const int R = tj.R[j], Cc = tj.Cc[j], RD = tj.RD[j], ldD = tj.ldD[j];
  int cb_span = (Cc > RD ? Cc : RD);
  int txt = (cb_span + 31) >> 5;
  int t = bid - tj.off[j];
  int bx = (t % txt) * 32;
  int by = (t / txt) * 32;
  __shared__ ushort_t tile[32][33];
  int tx = threadIdx.x & 31, ty = threadIdx.x >> 5;
  #pragma unroll
  for (int i = 0; i < 4; ++i) {
    int r = by + ty + i*8, c = bx + tx;
    ushort_t v = 0;
    if (r < R && c < Cc) v = f2bf(ldf(src, (size_t)r * Cc + c, inbf));
    tile[ty + i*8][tx] = v;
  }
  __syncthreads();
  #pragma unroll
  for (int i = 0; i < 4; ++i) {
    int dr = bx + ty + i*8, dc = by + tx;
    if (dr < RD && dc < ldD)
      dst[(size_t)dr * ldD + dc] = tile[tx][ty + i*8];
  }
}

// ---------------------------------------------------------------- MFMA GEMM
// Out[M, Nn] = act(A[M,K] @ WT[N,K]^T + bias) (+resid). Tile BM x BN x BK64,
// 256 thr / 4 waves. BM=64/BN=64: waves 1x4 (wave 64m x 16n, FN=1).
// BM=64/BN=128: waves 1x4 (wave 64m x 32n, FN=2) -> per K-step 16 MFMA : 12
// ds_read_b128 (vs 8:10 at BN=64) and A-panel re-fetch halves (gridx 12->6).
// LDS 24KB -> 6 blocks/CU (75% wave cap). Used for S2 (grid 1536 = 6/CU).
// Staging: global_load_lds w=16, LDS [row][k] 128 B rows, XOR chunk swizzle
// c' = c ^ (r&7) (measured 0 conflicts).
// Block-id: bijective XCD-chunked swizzle (T1/m204) -> each XCD owns a
// contiguous flat chunk; S2 FETCH measured 68.6MB (round-robin) -> 22.4MB.
// Round-5 lesson: avoid 128x128 (32KB LDS + tiny grids -> occupancy 8-30%,
// 20-40% regression). BN=128 keeps BM=64 staging and >=75% occupancy cap.
struct GB {
  const ushort_t* A[4]; const int* amap[4];
  const ushort_t* WT[4];
  const void* bias[4];
  void* out[4]; ushort_t* out2[4]; const int* omap[4];
};

template<int BM, int BN>
__global__ __launch_bounds__(256) void mgemm_k(
    GB gb, int lda, int ldb, int Nn, int K, int ldo,
    int act, int out_mode, const void* resid, int ldr, const int* __restrict__ flagp)
{
  constexpr int NA = BM / 32;          // A staging chunks per thread
  constexpr int NB = BN / 32;          // B staging chunks per thread
  constexpr int WN = (BM == 128) ? 2 : 4;   // waves along n
  constexpr int NSPAN = BN / WN;       // n-span per wave
  constexpr int FN = NSPAN / 16;       // n-frags per wave
  const int inbf = *flagp;
  const int z = blockIdx.z;

  const ushort_t* A  = gb.A[z];
  const int* amap    = gb.amap[z];
  const ushort_t* Bw = gb.WT[z];
  const void* bias   = gb.bias[z];
  void* Out          = gb.out[z];
  ushort_t* out2     = gb.out2[z];
  const int* omap    = gb.omap[z];

  __shared__ __align__(16) ushort_t As[BM * 64];
  __shared__ __align__(16) ushort_t Bs[BN * 64];

  const int tid  = threadIdx.x;
  const int w    = tid >> 6;
  const int lane = tid & 63;
  const int quad = lane >> 4;
  const int l15  = lane & 15;
  const int wm     = (BM == 128) ? (w >> 1) * 64 : 0;       // wave m offset
  const int wn_off = ((BM == 128) ? (w & 1) : w) * NSPAN;   // wave n offset

  // XCD-chunked bijective block swizzle (within a z-slice; all grids here have
  // (gx*gy)%8==0 so the z-offset keeps hw-id%8 alignment)
  const int gx = gridDim.x;
  const int nwg = gx * gridDim.y;
  int flat = blockIdx.y * gx + blockIdx.x;
  {
    const int q = nwg >> 3, rr = nwg & 7;
    const int xcd = flat & 7, wi = flat >> 3;
    flat = (xcd < rr ? xcd * (q + 1) : rr * (q + 1) + (xcd - rr) * q) + wi;
  }
  const int row0 = (flat / gx) * BM;
  const int col0 = (flat % gx) * BN;

  int agb[NA], bgb[NB], aldso[NA], bldso[NB];
  #pragma unroll
  for (int i = 0; i < NA; ++i) {
    int t = i*256 + tid;                // chunk id
    int r = t >> 3;
    int c = (t & 7) ^ (r & 7);          // swizzle involution
    int grow = row0 + r;
    if (amap) { int b = grow >> 10, l = grow & 1023; grow = (b << 10) + amap[l]; }
    agb[i] = grow * lda + c * 8;
    aldso[i] = (i*256 + w*64) * 16;
  }
  #pragma unroll
  for (int i = 0; i < NB; ++i) {
    int t = i*256 + tid;
    int r = t >> 3;
    int c = (t & 7) ^ (r & 7);
    bgb[i] = (col0 + r) * ldb + c * 8;
    bldso[i] = (i*256 + w*64) * 16;
  }

  f32x4 acc[4][FN];
  #pragma unroll
  for (int mi = 0; mi < 4; ++mi)
    #pragma unroll
    for (int ni = 0; ni < FN; ++ni)
      acc[mi][ni] = (f32x4){0.f, 0.f, 0.f, 0.f};

  const int sw = l15 & 7;

  for (int k0 = 0; k0 < K; k0 += 64) {
    #pragma unroll
    for (int i = 0; i < NA; ++i)
      gload_lds16(A + agb[i] + k0, (char*)As + aldso[i]);
    #pragma unroll
    for (int i = 0; i < NB; ++i)
      gload_lds16(Bw + bgb[i] + k0, (char*)Bs + bldso[i]);
    __syncthreads();

    #pragma unroll
    for (int ks = 0; ks < 2; ++ks) {
      short8 aF[4], bF[FN];
      #pragma unroll
      for (int mi = 0; mi < 4; ++mi)
        aF[mi] = *(const short8*)&As[(wm + mi*16 + l15) * 64 + (((quad + 4*ks) ^ sw) * 8)];
      #pragma unroll
      for (int ni = 0; ni < FN; ++ni)
        bF[ni] = *(const short8*)&Bs[(wn_off + ni*16 + l15) * 64 + (((quad + 4*ks) ^ sw) * 8)];
      #pragma unroll
      for (int mi = 0; mi < 4; ++mi)
        #pragma unroll
        for (int ni = 0; ni < FN; ++ni)
          acc[mi][ni] = __builtin_amdgcn_mfma_f32_16x16x32_bf16(aF[mi], bF[ni], acc[mi][ni], 0, 0, 0);
    }
    __syncthreads();
  }

  const int obf = (out_mode == 2) ? inbf : (out_mode == 0);
  #pragma unroll
  for (int ni = 0; ni < FN; ++ni) {
    int colg = col0 + wn_off + ni*16 + l15;
    if (colg >= Nn) continue;
    float bv = bias ? ldf(bias, colg, inbf) : 0.f;
    #pragma unroll
    for (int mi = 0; mi < 4; ++mi) {
      #pragma unroll
      for (int r = 0; r < 4; ++r) {
        int rowg = row0 + wm + mi*16 + quad*4 + r;
        int orow = rowg;
        if (omap) { int b = rowg >> 10, l = rowg & 1023; orow = (b << 10) + omap[l]; }
        float v = acc[mi][ni][r] + bv;
        if (out2 && colg < 64)
          out2[(size_t)orow * 64 + colg] = f2bf(colg < DR_ ? v : 0.f);
        if (act == 1)      v = (v > 20.f) ? v : log1pf(__expf(v));                  // softplus
        else if (act == 2) v = 0.5f * v * (1.f + erff(v * 0.70710678118654752f));   // gelu
        if (resid) v += ldf(resid, (size_t)orow * ldr + colg, inbf);
        size_t oi = (size_t)orow * ldo + colg;
        if (obf) ((ushort_t*)Out)[oi] = f2bf(v);
        else     ((float*)Out)[oi]    = v;
      }
    }
  }
}

// ---------------------------------------------------------------- conv(K=4)+silu
__global__ __launch_bounds__(256) void conv_silu_k(
    const ushort_t* __restrict__ u,
    const void* __restrict__ cw0, const void* __restrict__ cw1,
    const void* __restrict__ cb0, const void* __restrict__ cb1,
    ushort_t* __restrict__ uc, const int* __restrict__ flagp)
{
  const int inbf = *flagp;
  int g = blockIdx.x * 256 + threadIdx.x;
  int c = g % C_;
  int row = g / C_;
  int l = row & 1023;
  const void* cw = (row >> 12) ? cw1 : cw0;
  const void* cb = (row >> 12) ? cb1 : cb0;
  float w0 = ldf(cw, c*4+0, inbf), w1 = ldf(cw, c*4+1, inbf);
  float w2 = ldf(cw, c*4+2, inbf), w3 = ldf(cw, c*4+3, inbf);
  const ushort_t* up = u + (size_t)(row - l) * C_ + c;
  float s = ldf(cb, c, inbf);
  if (l >= 3) s += w0 * bf2f(up[(size_t)(l-3) * C_]);
  if (l >= 2) s += w1 * bf2f(up[(size_t)(l-2) * C_]);
  if (l >= 1) s += w2 * bf2f(up[(size_t)(l-1) * C_]);
  s += w3 * bf2f(up[(size_t)l * C_]);
  s = s / (1.f + __expf(-s));
  uc[g] = f2bf(s);
}

// ---------------------------------------------------------------- segmented scan
// State-parallel (4 lanes/channel, 4 states each) + LDS-staged operands.
// Round-3 lesson: state-parallel WITHOUT staging quadruples scalar VMEM and
// each wave load fetches 32 useful bytes -> slower. Fix: stage dt/uc (and B/C)
// tiles into LDS with coalesced global_load_lds (16B/lane), read per-l values
// from LDS (4-lane same-address = broadcast). pass3 also accumulates output in
// an f32 LDS tile and writes y via a fully-coalesced short8 epilogue.
// Rounds 7-9 lesson: SEG=32 (2x occupancy), 1-thread/channel (fewer ops), and
// grid-barrier fusion were all null or fatal; this structure is the floor.
__global__ __launch_bounds__(256) void scan_pass1(
    const ushort_t* __restrict__ dt, const ushort_t* __restrict__ uc,
    const float* __restrict__ dbl,
    const void* __restrict__ Alog_cw, const void* __restrict__ Alog_ccw,
    ushort_t* __restrict__ P, ushort_t* __restrict__ Q,
    const int* __restrict__ flagp)
{
  const int inbf = *flagp;
  const int db = blockIdx.z, d = db >> 2;
  const int s = blockIdx.y;
  const int tid = threadIdx.x;
  const int cl = tid >> 2;             // channel-local 0..63
  const int n4 = tid & 3;              // state group (4 states)
  const int c0 = blockIdx.x * 64;
  const int c = c0 + cl;
  const int l0 = s * SEG_;

  __shared__ __align__(16) float    BsS[SEG_ * 16];   // 4KB  [l][16] B cols
  __shared__ __align__(16) ushort_t dtS[SEG_ * 64];   // 8KB  [l][64]
  __shared__ __align__(16) ushort_t ucS[SEG_ * 64];   // 8KB
  {
    // B tile: 256 chunks x 16B (row l, 4 f32 per chunk)
    {
      int row = tid >> 2, col = (tid & 3) * 4;
      gload_lds16(dbl + ((size_t)db * L_ + l0 + row) * 80 + DR_ + col,
                  (char*)BsS + tid * 16);
    }
    // dt/uc tiles: 512 chunks x 16B each (row l, 8 bf16 per chunk)
    #pragma unroll
    for (int i = 0; i < 2; ++i) {
      int ch = i * 256 + tid;
      int row = ch >> 3, col = (ch & 7) * 8;
      size_t go = ((size_t)db * L_ + l0 + row) * C_ + c0 + col;
      gload_lds16(dt + go, (char*)dtS + ch * 16);
      gload_lds16(uc + go, (char*)ucS + ch * 16);
    }
  }
  __syncthreads();

  const void* Alog = d ? Alog_ccw : Alog_cw;
  float a[4];
  #pragma unroll
  for (int j = 0; j < 4; ++j) a[j] = -__expf(ldf(Alog, c * N_ + n4*4 + j, inbf));

  float h[4] = {0.f, 0.f, 0.f, 0.f};
  float S = 0.f;

  #pragma unroll 8
  for (int l = 0; l < SEG_; ++l) {
    float dtv = bf2f(dtS[l * 64 + cl]);
    float ucv = bf2f(ucS[l * 64 + cl]);
    float dtu = dtv * ucv;
    S += dtv;
    f32x4 bq = *(const f32x4*)&BsS[l * 16 + n4 * 4];
    #pragma unroll
    for (int j = 0; j < 4; ++j) { float dA = __expf(dtv*a[j]); h[j] = h[j]*dA + dtu*bq[j]; }
  }
  size_t idx = (((size_t)db * NSEG_ + s) * C_ + c) * N_ + n4*4;
  u16x4 pv, qv;
  #pragma unroll
  for (int j = 0; j < 4; ++j) { pv[j] = f2bf(__expf(a[j] * S)); qv[j] = f2bf(h[j]); }
  *(u16x4*)&P[idx] = pv;
  *(u16x4*)&Q[idx] = qv;
}

__global__ __launch_bounds__(256) void scan_pass2(
    ushort_t* __restrict__ P, ushort_t* __restrict__ Q)
{
  size_t g = (size_t)blockIdx.x * 256 + threadIdx.x;
  size_t db = g / (C_ * N_);
  size_t cn = g % (C_ * N_);
  float h = 0.f;
  #pragma unroll
  for (int s = 0; s < NSEG_; ++s) {
    size_t off = (db * NSEG_ + s) * (C_ * N_) + cn;
    float p = bf2f(P[off]), q = bf2f(Q[off]);
    Q[off] = f2bf(h);
    h = h * p + q;
  }
}

__global__ __launch_bounds__(256) void scan_pass3(
    const ushort_t* __restrict__ dt, const ushort_t* __restrict__ uc,
    const float* __restrict__ dbl, const ushort_t* __restrict__ z,
    const void* __restrict__ Alog_cw, const void* __restrict__ Alog_ccw,
    const void* __restrict__ D_cw, const void* __restrict__ D_ccw,
    const ushort_t* __restrict__ Q, ushort_t* __restrict__ y,
    const int* __restrict__ flagp)
{
  const int inbf = *flagp;
  const int db = blockIdx.z, d = db >> 2;
  const int s = blockIdx.y;
  const int tid = threadIdx.x;
  const int cl = tid >> 2;             // channel-local 0..63
  const int n4 = tid & 3;              // state group (4 states)
  const int c0 = blockIdx.x * 64;
  const int c = c0 + cl;
  const int l0 = s * SEG_;

  __shared__ __align__(16) float    BsS[SEG_ * 32];   // 8KB  [l][32] B|C cols
  __shared__ __align__(16) ushort_t dtS[SEG_ * 64];   // 8KB
  __shared__ __align__(16) ushort_t ucS[SEG_ * 64];   // 8KB
  __shared__ __align__(16) float    yS [SEG_ * 64];   // 16KB pre-silu output
  {
    // B|C tile: 512 chunks x 16B
    #pragma unroll
    for (int i = 0; i < 2; ++i) {
      int ch = i * 256 + tid;
      int row = ch >> 3, col = (ch & 7) * 4;
      gload_lds16(dbl + ((size_t)db * L_ + l0 + row) * 80 + DR_ + col,
                  (char*)BsS + ch * 16);
    }
    // dt/uc tiles: 512 chunks x 16B each
    #pragma unroll
    for (int i = 0; i < 2; ++i) {
      int ch = i * 256 + tid;
      int row = ch >> 3, col = (ch & 7) * 8;
      size_t go = ((size_t)db * L_ + l0 + row) * C_ + c0 + col;
      gload_lds16(dt + go, (char*)dtS + ch * 16);
      gload_lds16(uc + go, (char*)ucS + ch * 16);
    }
  }
  __syncthreads();

  const void* Alog = d ? Alog_ccw : Alog_cw;
  const void* Dp   = d ? D_ccw   : D_cw;
  float a[4];
  #pragma unroll
  for (int j = 0; j < 4; ++j) a[j] = -__expf(ldf(Alog, c * N_ + n4*4 + j, inbf));
  const float dvc = ldf(Dp, c, inbf);

  size_t idx = (((size_t)db * NSEG_ + s) * C_ + c) * N_ + n4*4;
  float h[4];
  #pragma unroll
  for (int j = 0; j < 4; ++j) h[j] = bf2f(Q[idx + j]);

  #pragma unroll 4
  for (int l = 0; l < SEG_; ++l) {
    float dtv = bf2f(dtS[l * 64 + cl]);
    float ucv = bf2f(ucS[l * 64 + cl]);
    float dtu = dtv * ucv;
    f32x4 bq = *(const f32x4*)&BsS[l * 32 + n4 * 4];
    f32x4 cq = *(const f32x4*)&BsS[l * 32 + 16 + n4 * 4];
    float yv = 0.f;
    #pragma unroll
    for (int j = 0; j < 4; ++j) { float dA = __expf(dtv*a[j]); h[j] = h[j]*dA + dtu*bq[j]; yv += h[j]*cq[j]; }
    // reduce partial yv across the 4 state-group lanes
    yv += __shfl_xor(yv, 1);
    yv += __shfl_xor(yv, 2);
    if (n4 == 0) yS[l * 64 + cl] = yv + dvc * ucv;
  }
  __syncthreads();

  // coalesced epilogue: o = yS * silu(z), short8 stores
  #pragma unroll
  for (int i = 0; i < 2; ++i) {
    int ch = i * 256 + tid;
    int row = ch >> 3, col = (ch & 7) * 8;
    size_t go = ((size_t)db * L_ + l0 + row) * C_ + c0 + col;
    short8 zr = *(const short8*)(z + go);
    f32x4 y0 = *(const f32x4*)&yS[row * 64 + col];
    f32x4 y1 = *(const f32x4*)&yS[row * 64 + col + 4];
    short8 res;
    #pragma unroll
    for (int j = 0; j < 4; ++j) {
      float zv = bf2f((ushort_t)zr[j]);
      res[j] = (short)f2bf(y0[j] * zv / (1.f + __expf(-zv)));
    }
    #pragma unroll
    for (int j = 0; j < 4; ++j) {
      float zv = bf2f((ushort_t)zr[4 + j]);
      res[4 + j] = (short)f2bf(y1[j] * zv / (1.f + __expf(-zv)));
    }
    *(short8*)(y + go) = res;
  }
}

// ---------------------------------------------------------------- launch
extern "C" void kernel_launch(void* const* d_in, const int* in_sizes, int n_in,
                              void* d_out, int out_size, void* d_ws, size_t ws_size,
                              hipStream_t stream)
{
  const void* x      = d_in[0];
  const void* norm_w = d_in[1];
  const void* norm_b = d_in[2];
  const void* in_w[2]    = { d_in[3],  d_in[12] };
  const void* conv_w[2]  = { d_in[4],  d_in[13] };
  const void* conv_b[2]  = { d_in[5],  d_in[14] };
  const void* xproj_w[2] = { d_in[6],  d_in[15] };
  const void* dtp_w[2]   = { d_in[7],  d_in[16] };
  const void* dtp_b[2]   = { d_in[8],  d_in[17] };
  const void* A_log[2]   = { d_in[9],  d_in[18] };
  const void* Dvec[2]    = { d_in[10], d_in[19] };
  const void* out_w[2]   = { d_in[11], d_in[20] };
  const void* fus_w1 = d_in[21];
  const void* fus_b1 = d_in[22];
  const void* fus_w2 = d_in[23];
  const void* fus_b2 = d_in[24];

  char* base = (char*)d_ws;
  int*      IDX  = (int*)base;
  int*      FLAG = (int*)(base + 8192);
  ushort_t* XN   = (ushort_t*)(base + 8448);
  ushort_t* U    = (ushort_t*)(base + 6299904);
  ushort_t* Z    = (ushort_t*)(base + 18882816);
  ushort_t* UC   = (ushort_t*)(base + 31465728);
  float*    DBL  = (float*)(base + 44048640);
  ushort_t* Y    = (ushort_t*)(base + 46670080);
  // lifetime aliases
  ushort_t* DT    = U;                                  // S5 out, scan in
  ushort_t* FUSED = Z;                                  // S7 out, S8 in
  ushort_t* HBUF  = XN;                                 // S8 out, S9 in
  ushort_t* SP = (ushort_t*)(base + 8448);              // scan only (bf16)
  ushort_t* SQ = SP + (size_t)2 * 4 * NSEG_ * C_ * N_;
  ushort_t* DTC = XN;                                   // S4 out2, S5 in
  ushort_t* INWT = UC;                                  // [2][1536][768], S2
  ushort_t* uout = (ushort_t*)d_out;
  ushort_t* XPJT = uout;                                // [2][128][768], S4
  ushort_t* DTPT = uout + 196608;                       // [2][768][64],  S5
  ushort_t* OWT  = uout + 294912;                       // [2][768][768], S7
  ushort_t* FW1T = U;                                   // [768][1536], S8
  ushort_t* FW2T = U + (size_t)768 * 1536;              // [768][768],  S9

  const size_t SD = (size_t)M_ * C_;

  // ---- prep: weight transposes + layernorm + spiral idx + FLAG, one dispatch
  {
    TJ tj; tj.njobs = 8;
    for (int d = 0; d < 2; ++d) {
      int j = d;
      tj.src[j]=in_w[d]; tj.dst[j]=INWT+(size_t)d*1536*768;
      tj.R[j]=768; tj.Cc[j]=1536; tj.RD[j]=1536; tj.ldD[j]=768;
    }
    for (int d = 0; d < 2; ++d) {
      int j = 2+d;
      tj.src[j]=xproj_w[d]; tj.dst[j]=XPJT+(size_t)d*128*768;
      tj.R[j]=768; tj.Cc[j]=80; tj.RD[j]=128; tj.ldD[j]=768;
    }
    for (int d = 0; d < 2; ++d) {
      int j = 4+d;
      tj.src[j]=dtp_w[d]; tj.dst[j]=DTPT+(size_t)d*768*64;
      tj.R[j]=48; tj.Cc[j]=768; tj.RD[j]=768; tj.ldD[j]=64;
    }
    for (int d = 0; d < 2; ++d) {
      int j = 6+d;
      tj.src[j]=out_w[d]; tj.dst[j]=OWT+(size_t)d*768*768;
      tj.R[j]=768; tj.Cc[j]=768; tj.RD[j]=768; tj.ldD[j]=768;
    }
    tj.off[0] = 0;
    for (int j = 0; j < 8; ++j) {
      int cspan = tj.Cc[j] > tj.RD[j] ? tj.Cc[j] : tj.RD[j];
      int rspan = tj.R[j] > tj.ldD[j] ? tj.R[j] : tj.ldD[j];
      tj.off[j+1] = tj.off[j] + ((cspan+31)>>5) * ((rspan+31)>>5);
    }
    int nblk = tj.off[8] + M_ + 1;
    hipLaunchKernelGGL(prep_k, dim3(nblk), dim3(256), 0, stream,
        tj, x, norm_w, norm_b, XN, IDX, IDX + L_, FLAG);
  }

  GB gb;
  for (int i = 0; i < 4; ++i) { gb.out2[i] = nullptr; gb.omap[i] = nullptr; gb.amap[i] = nullptr; gb.bias[i] = nullptr; }

  // ---- S2: in_proj, z = (d, u/z half), BM=64 BN=128, grid 6x64x4 = 1536
  for (int zz = 0; zz < 4; ++zz) {
    int d = zz >> 1, half = zz & 1;
    gb.A[zz] = XN; gb.amap[zz] = IDX + d * L_;
    gb.WT[zz] = INWT + (size_t)d*1536*768 + (size_t)half*768*768;
    gb.bias[zz] = nullptr;
    gb.out[zz] = (void*)((half ? Z : U) + d * SD); gb.out2[zz] = nullptr; gb.omap[zz] = nullptr;
  }
  hipLaunchKernelGGL((mgemm_k<64,128>), dim3(6, 64, 4), dim3(256), 0, stream,
      gb, C_, C_, C_, C_, C_, 0, 0, (const void*)nullptr, 0, FLAG);

  // ---- S3: conv + silu (both dirs, one dispatch)
  hipLaunchKernelGGL(conv_silu_k, dim3(2*M_*C_/256), dim3(256), 0, stream,
      U, conv_w[0], conv_w[1], conv_b[0], conv_b[1], UC, FLAG);

  // ---- S4: xproj -> DBL fp32 (+fused dtc), BM=64 BN=64, Nn=80, grid 2x64x2
  for (int zz = 0; zz < 2; ++zz) {
    gb.A[zz] = UC + zz * SD; gb.amap[zz] = nullptr;
    gb.WT[zz] = XPJT + (size_t)zz*128*768;
    gb.bias[zz] = nullptr;
    gb.out[zz] = (void*)(DBL + (size_t)zz * M_ * 80);
    gb.out2[zz] = DTC + (size_t)zz * M_ * 64;
    gb.omap[zz] = nullptr;
  }
  hipLaunchKernelGGL((mgemm_k<64,64>), dim3(2, 64, 2), dim3(256), 0, stream,
      gb, C_, C_, 80, C_, 80, 0, 1, (const void*)nullptr, 0, FLAG);

  // ---- S5: dt = softplus(dtc @ dtp_w + dtp_b), K=64, BM=64 BN=64, grid 12x64x2
  for (int zz = 0; zz < 2; ++zz) {
    gb.A[zz] = DTC + (size_t)zz * M_ * 64; gb.amap[zz] = nullptr;
    gb.WT[zz] = DTPT + (size_t)zz*768*64;
    gb.bias[zz] = dtp_b[zz];
    gb.out[zz] = (void*)(DT + zz * SD); gb.out2[zz] = nullptr; gb.omap[zz] = nullptr;
  }
  hipLaunchKernelGGL((mgemm_k<64,64>), dim3(12, 64, 2), dim3(256), 0, stream,
      gb, 64, 64, C_, 64, C_, 1, 0, (const void*)nullptr, 0, FLAG);

  // ---- S6: segmented selective scan (state-parallel + LDS-staged)
  hipLaunchKernelGGL(scan_pass1, dim3(12, NSEG_, 8), dim3(256), 0, stream,
      DT, UC, DBL, A_log[0], A_log[1], SP, SQ, FLAG);
  hipLaunchKernelGGL(scan_pass2, dim3(8 * C_ * N_ / 256), dim3(256), 0, stream, SP, SQ);
  hipLaunchKernelGGL(scan_pass3, dim3(12, NSEG_, 8), dim3(256), 0, stream,
      DT, UC, DBL, Z, A_log[0], A_log[1], Dvec[0], Dvec[1], SQ, Y, FLAG);

  // ---- batched transposes #2 (fus weights; U region free after scan)
  {
    TJ tj; tj.njobs = 2;
    tj.src[0]=fus_w1; tj.dst[0]=FW1T; tj.R[0]=1536; tj.Cc[0]=768; tj.RD[0]=768; tj.ldD[0]=1536;
    tj.src[1]=fus_w2; tj.dst[1]=FW2T; tj.R[1]=768;  tj.Cc[1]=768; tj.RD[1]=768; tj.ldD[1]=768;
    tj.off[0] = 0;
    for (int j = 0; j < 2; ++j) {
      int cspan = tj.Cc[j] > tj.RD[j] ? tj.Cc[j] : tj.RD[j];
      int rspan = tj.R[j] > tj.ldD[j] ? tj.R[j] : tj.ldD[j];
      tj.off[j+1] = tj.off[j] + ((cspan+31)>>5) * ((rspan+31)>>5);
    }
    hipLaunchKernelGGL(tbatch_k, dim3(tj.off[2]), dim3(256), 0, stream, tj, FLAG);
  }

  // ---- S7: out_proj with spiral-inverse scatter, BM=64 BN=64, grid 12x64x2
  for (int zz = 0; zz < 2; ++zz) {
    gb.A[zz] = Y + zz * SD; gb.amap[zz] = nullptr;
    gb.WT[zz] = OWT + (size_t)zz*768*768;
    gb.bias[zz] = nullptr;
    gb.out[zz] = (void*)(FUSED + zz * C_); gb.out2[zz] = nullptr; gb.omap[zz] = IDX + zz * L_;
  }
  hipLaunchKernelGGL((mgemm_k<64,64>), dim3(12, 64, 2), dim3(256), 0, stream,
      gb, C_, C_, C_, C_, 2*C_, 0, 0, (const void*)nullptr, 0, FLAG);

  // ---- S8: h = gelu(fused @ fus_w1 + fus_b1), K=1536, BM=64 BN=64, grid 12x64x1
  gb.A[0] = FUSED; gb.amap[0] = nullptr;
  gb.WT[0] = FW1T; gb.bias[0] = fus_b1;
  gb.out[0] = (void*)HBUF; gb.out2[0] = nullptr; gb.omap[0] = nullptr;
  hipLaunchKernelGGL((mgemm_k<64,64>), dim3(12, 64, 1), dim3(256), 0, stream,
      gb, 2*C_, 2*C_, C_, 2*C_, C_, 2, 0, (const void*)nullptr, 0, FLAG);

  // ---- S9: out = h @ fus_w2 + fus_b2 + x, BM=64 BN=64, grid 12x64x1
  gb.A[0] = HBUF; gb.amap[0] = nullptr;
  gb.WT[0] = FW2T; gb.bias[0] = fus_b2;
  gb.out[0] = d_out; gb.out2[0] = nullptr; gb.omap[0] = nullptr;
  hipLaunchKernelGGL((mgemm_k<64,64>), dim3(12, 64, 1), dim3(256), 0, stream,
      gb, C_, C_, C_, C_, C_, 0, 2, x, C_, FLAG);
}

// Round 12
// 349.920 us; speedup vs baseline: 1.1334x; 1.1334x over previous
//
#include <hip/hip_runtime.h>

typedef unsigned short ushort_t;
typedef __attribute__((ext_vector_type(8))) short short8;
typedef __attribute__((ext_vector_type(4))) float f32x4;
typedef __attribute__((ext_vector_type(4))) unsigned short u16x4;

#define B_ 4
#define L_ 1024
#define C_ 768
#define N_ 16
#define DR_ 48
#define HW_ 32
#define M_ (B_*L_)   // 4096 rows
#define SEG_ 64      // scan segment length
#define NSEG_ 16     // L_/SEG_

// Workspace layout (byte offsets), total 59,252,992 B:
//   0        IDX   (2*1024 int)
//   8192     FLAG
//   8448     XN region: XN -> DTC -> {SP,SQ bf16} -> HBUF
//   6299904  U region: U -> DT -> {fus_w1^T, fus_w2^T}
//   18882816 Z region: Z -> FUSED
//   31465728 UC region: in_w^T -> UC
//   44048640 DBL 2*M*80 f32
//   46670080 Y 2*M*C u16
// d_out doubles as scratch for {xproj^T, dtp^T, out_w^T} until S7 (dead til S9).
//
// Session ledger (what was tried, what it did):
//   R2  analytic parallel spiral idx     : prep 67->~22us   (+43us)  KEEP
//   R4  scan state-parallel + LDS staging: scan p3 62->45us (+26us)  KEEP
//   R5  GEMM XCD-chunked block swizzle   : S2 FETCH 68.6->22.4MB     KEEP
//   R5  GEMM 128x128 tiles               : -20..40% (occupancy)      REVERTED
//   R7  scan SEG=32 (2x occupancy)       : null (VALU-issue bound)   REVERTED
//   R8  scan 1-thread/channel (fewer ops): null                      REVERTED
//   R9  scan 3-pass fusion, grid barrier : harness crash             REVERTED
//   R11 S2 BN=128                        : -7% (WRITE +29%, occ 35%) REVERTED
// Best verified: 370.7us (R10). Scan ~44us/pass is a floor across 4
// structures; 64x64 GEMM beats all wider tiles at these shapes.

__device__ __forceinline__ float bf2f(ushort_t u) {
  union { unsigned int i; float f; } v; v.i = ((unsigned int)u) << 16; return v.f;
}
__device__ __forceinline__ ushort_t f2bf(float f) {
  union { float f; unsigned int i; } v; v.f = f;
  unsigned int x = v.i;
  return (ushort_t)((x + 0x7fffu + ((x >> 16) & 1u)) >> 16);
}
__device__ __forceinline__ float ldf(const void* p, size_t i, int bf) {
  return bf ? bf2f(((const ushort_t*)p)[i]) : ((const float*)p)[i];
}
// bf16-vs-fp32 detect on x's first 256 words. Wave-parallel: each of 64 lanes
// checks 4 consecutive u16 (one coalesced 8B load), then one ballot.
// Must be called with all 64 lanes of the wave active.
__device__ __forceinline__ int detect_bf(const void* x) {
  const ushort_t* u = (const ushort_t*)x;
  int lane = threadIdx.x & 63;
  const ushort_t* p = u + lane * 4;
  int bad = 0;
  #pragma unroll
  for (int i = 0; i < 4; ++i) {
    int e = (p[i] >> 7) & 0xFF;
    bad |= (e < 90 || e > 141);
  }
  return (__ballot(bad) == 0ull) ? 1 : 0;
}
// async global->LDS, 16 B per lane; lds dest = wave-uniform base + lane*16
__device__ __forceinline__ void gload_lds16(const void* g, void* lds) {
  __builtin_amdgcn_global_load_lds(
      (const __attribute__((address_space(1))) unsigned int*)g,
      (__attribute__((address_space(3))) unsigned int*)lds, 16, 0, 0);
}

// ---------------------------------------------------------------- prep kernel
// One dispatch: blocks [0,oT) weight transposes, [oT,oT+4096) layernorm rows,
// block oT+4096 spiral-idx + FLAG write. All independent.
struct TJ {
  const void* src[8]; ushort_t* dst[8];
  int R[8], Cc[8], RD[8], ldD[8];
  int off[9]; int njobs;
};

__global__ __launch_bounds__(256) void prep_k(
    TJ tj, const void* __restrict__ x, const void* __restrict__ nw,
    const void* __restrict__ nb, ushort_t* __restrict__ xn,
    int* idx_cw, int* idx_ccw, int* flag)
{
  const int oT = tj.off[tj.njobs];
  int bid = blockIdx.x;
  // one wave-parallel detect per block, all lanes active (uniform path)
  const int inbf = detect_bf(x);

  if (bid < oT) {                       // ---- transpose job
    int j = 0;
    while (bid >= tj.off[j+1]) ++j;
    const void* src = tj.src[j];
    ushort_t* dst = tj.dst[j];
    const int R = tj.R[j], Cc = tj.Cc[j], RD = tj.RD[j], ldD = tj.ldD[j];
    int cb_span = (Cc > RD ? Cc : RD);
    int txt = (cb_span + 31) >> 5;
    int t = bid - tj.off[j];
    int bx = (t % txt) * 32;
    int by = (t / txt) * 32;
    __shared__ ushort_t tile[32][33];
    int tx = threadIdx.x & 31, ty = threadIdx.x >> 5;
    #pragma unroll
    for (int i = 0; i < 4; ++i) {
      int r = by + ty + i*8, c = bx + tx;
      ushort_t v = 0;
      if (r < R && c < Cc) v = f2bf(ldf(src, (size_t)r * Cc + c, inbf));
      tile[ty + i*8][tx] = v;
    }
    __syncthreads();
    #pragma unroll
    for (int i = 0; i < 4; ++i) {
      int dr = bx + ty + i*8, dc = by + tx;
      if (dr < RD && dc < ldD)
        dst[(size_t)dr * ldD + dc] = tile[tx][ty + i*8];
    }
    return;
  }
  bid -= oT;
  if (bid < M_) {                       // ---- layernorm row
    int tid = threadIdx.x;
    size_t o0 = (size_t)bid * C_;
    float v0 = ldf(x, o0 + tid,       inbf);
    float v1 = ldf(x, o0 + tid + 256, inbf);
    float v2 = ldf(x, o0 + tid + 512, inbf);
    float s = v0 + v1 + v2, s2 = v0*v0 + v1*v1 + v2*v2;
    for (int o = 32; o > 0; o >>= 1) { s += __shfl_down(s, o); s2 += __shfl_down(s2, o); }
    __shared__ float ss[4], ss2[4];
    if ((tid & 63) == 0) { ss[tid >> 6] = s; ss2[tid >> 6] = s2; }
    __syncthreads();
    s  = ss[0] + ss[1] + ss[2] + ss[3];
    s2 = ss2[0] + ss2[1] + ss2[2] + ss2[3];
    float mean = s * (1.f / C_);
    float var  = s2 * (1.f / C_) - mean * mean;
    float inv  = rsqrtf(var + 1e-6f);
    xn[o0 + tid]       = f2bf((v0 - mean) * inv * ldf(nw, tid,     inbf) + ldf(nb, tid,     inbf));
    xn[o0 + tid + 256] = f2bf((v1 - mean) * inv * ldf(nw, tid+256, inbf) + ldf(nb, tid+256, inbf));
    xn[o0 + tid + 512] = f2bf((v2 - mean) * inv * ldf(nw, tid+512, inbf) + ldf(nb, tid+512, inbf));
    return;
  }
  // ---- setup block: PARALLEL analytic spiral-index generation.
  // Ring r of the WxW spiral starts at offset S_r = 4r(W-r); ring side s=W-2r;
  // within-ring position q maps closed-form to (i,j) for each of the 4 legs.
  {
    int tid = threadIdx.x;
    #pragma unroll
    for (int k = 0; k < 4; ++k) {
      int p = tid * 4 + k;                      // spiral position, 0..1023
      int r = 0;
      while (r < (HW_/2 - 1) && p >= 4*(r+1)*(HW_-(r+1))) ++r;
      int q = p - 4*r*(HW_-r);
      int s = HW_ - 2*r;
      int hi = HW_ - 1 - r;
      int icw, jcw, iccw, jccw;
      if (q < s)              { icw = r;                  jcw = r + q; }
      else if (q < 2*s-1)     { icw = r + 1 + (q - s);    jcw = hi; }
      else if (q < 3*s-2)     { icw = hi;                 jcw = hi - 1 - (q - (2*s-1)); }
      else                    { icw = hi - 1 - (q - (3*s-2)); jcw = r; }
      if (q < s)              { iccw = r;                 jccw = hi - q; }
      else if (q < 2*s-1)     { iccw = r + 1 + (q - s);   jccw = r; }
      else if (q < 3*s-2)     { iccw = hi;                jccw = r + 1 + (q - (2*s-1)); }
      else                    { iccw = hi - 1 - (q - (3*s-2)); jccw = hi; }
      idx_cw[p]  = icw  * HW_ + jcw;
      idx_ccw[p] = iccw * HW_ + jccw;
    }
    if (tid == 0) *flag = inbf;
  }
}

// ---------------------------------------------------------------- batched transpose
__global__ __launch_bounds__(256) void tbatch_k(TJ tj, const int* __restrict__ flagp) {
  const int inbf = *flagp;
  int bid = blockIdx.x;
  int j = 0;
  while (bid >= tj.off[j+1]) ++j;
  const void* src = tj.src[j];
  ushort_t* dst = tj.dst[j];
  const int R = tj.R[j], Cc = tj.Cc[j], RD = tj.RD[j], ldD = tj.ldD[j];
  int cb_span = (Cc > RD ? Cc : RD);
  int txt = (cb_span + 31) >> 5;
  int t = bid - tj.off[j];
  int bx = (t % txt) * 32;
  int by = (t / txt) * 32;
  __shared__ ushort_t tile[32][33];
  int tx = threadIdx.x & 31, ty = threadIdx.x >> 5;
  #pragma unroll
  for (int i = 0; i < 4; ++i) {
    int r = by + ty + i*8, c = bx + tx;
    ushort_t v = 0;
    if (r < R && c < Cc) v = f2bf(ldf(src, (size_t)r * Cc + c, inbf));
    tile[ty + i*8][tx] = v;
  }
  __syncthreads();
  #pragma unroll
  for (int i = 0; i < 4; ++i) {
    int dr = bx + ty + i*8, dc = by + tx;
    if (dr < RD && dc < ldD)
      dst[(size_t)dr * ldD + dc] = tile[tx][ty + i*8];
  }
}

// ---------------------------------------------------------------- MFMA GEMM
// Out[M, Nn] = act(A[M,K] @ WT[N,K]^T + bias) (+resid). Tile BM x BN x BK64,
// 256 thr / 4 waves. BM=64: waves 1x4 (wave 64m x 16n).
// Staging: global_load_lds w=16, LDS [row][k] 128 B rows, XOR chunk swizzle
// c' = c ^ (r&7) (measured 0 conflicts).
// Block-id: bijective XCD-chunked swizzle (T1/m204) -> each XCD owns a
// contiguous flat chunk; S2 FETCH measured 68.6MB (round-robin) -> 22.4MB.
// Tile space fully explored: 64x64 beats 128x128 (R5, -20..40%) and 64x128
// (R11, -7%, WRITE +29%) — at M=4096/N=768 these GEMMs want max block count
// and a compact per-block write footprint.
struct GB {
  const ushort_t* A[4]; const int* amap[4];
  const ushort_t* WT[4];
  const void* bias[4];
  void* out[4]; ushort_t* out2[4]; const int* omap[4];
};

template<int BM, int BN>
__global__ __launch_bounds__(256) void mgemm_k(
    GB gb, int lda, int ldb, int Nn, int K, int ldo,
    int act, int out_mode, const void* resid, int ldr, const int* __restrict__ flagp)
{
  constexpr int NA = BM / 32;          // A staging chunks per thread
  constexpr int NB = BN / 32;          // B staging chunks per thread
  constexpr int WN = (BM == 128) ? 2 : 4;   // waves along n
  constexpr int NSPAN = BN / WN;       // n-span per wave
  constexpr int FN = NSPAN / 16;       // n-frags per wave
  const int inbf = *flagp;
  const int z = blockIdx.z;

  const ushort_t* A  = gb.A[z];
  const int* amap    = gb.amap[z];
  const ushort_t* Bw = gb.WT[z];
  const void* bias   = gb.bias[z];
  void* Out          = gb.out[z];
  ushort_t* out2     = gb.out2[z];
  const int* omap    = gb.omap[z];

  __shared__ __align__(16) ushort_t As[BM * 64];
  __shared__ __align__(16) ushort_t Bs[BN * 64];

  const int tid  = threadIdx.x;
  const int w    = tid >> 6;
  const int lane = tid & 63;
  const int quad = lane >> 4;
  const int l15  = lane & 15;
  const int wm     = (BM == 128) ? (w >> 1) * 64 : 0;       // wave m offset
  const int wn_off = ((BM == 128) ? (w & 1) : w) * NSPAN;   // wave n offset

  // XCD-chunked bijective block swizzle (within a z-slice; all grids here have
  // (gx*gy)%8==0 so the z-offset keeps hw-id%8 alignment)
  const int gx = gridDim.x;
  const int nwg = gx * gridDim.y;
  int flat = blockIdx.y * gx + blockIdx.x;
  {
    const int q = nwg >> 3, rr = nwg & 7;
    const int xcd = flat & 7, wi = flat >> 3;
    flat = (xcd < rr ? xcd * (q + 1) : rr * (q + 1) + (xcd - rr) * q) + wi;
  }
  const int row0 = (flat / gx) * BM;
  const int col0 = (flat % gx) * BN;

  int agb[NA], bgb[NB], aldso[NA], bldso[NB];
  #pragma unroll
  for (int i = 0; i < NA; ++i) {
    int t = i*256 + tid;                // chunk id
    int r = t >> 3;
    int c = (t & 7) ^ (r & 7);          // swizzle involution
    int grow = row0 + r;
    if (amap) { int b = grow >> 10, l = grow & 1023; grow = (b << 10) + amap[l]; }
    agb[i] = grow * lda + c * 8;
    aldso[i] = (i*256 + w*64) * 16;
  }
  #pragma unroll
  for (int i = 0; i < NB; ++i) {
    int t = i*256 + tid;
    int r = t >> 3;
    int c = (t & 7) ^ (r & 7);
    bgb[i] = (col0 + r) * ldb + c * 8;
    bldso[i] = (i*256 + w*64) * 16;
  }

  f32x4 acc[4][FN];
  #pragma unroll
  for (int mi = 0; mi < 4; ++mi)
    #pragma unroll
    for (int ni = 0; ni < FN; ++ni)
      acc[mi][ni] = (f32x4){0.f, 0.f, 0.f, 0.f};

  const int sw = l15 & 7;

  for (int k0 = 0; k0 < K; k0 += 64) {
    #pragma unroll
    for (int i = 0; i < NA; ++i)
      gload_lds16(A + agb[i] + k0, (char*)As + aldso[i]);
    #pragma unroll
    for (int i = 0; i < NB; ++i)
      gload_lds16(Bw + bgb[i] + k0, (char*)Bs + bldso[i]);
    __syncthreads();

    #pragma unroll
    for (int ks = 0; ks < 2; ++ks) {
      short8 aF[4], bF[FN];
      #pragma unroll
      for (int mi = 0; mi < 4; ++mi)
        aF[mi] = *(const short8*)&As[(wm + mi*16 + l15) * 64 + (((quad + 4*ks) ^ sw) * 8)];
      #pragma unroll
      for (int ni = 0; ni < FN; ++ni)
        bF[ni] = *(const short8*)&Bs[(wn_off + ni*16 + l15) * 64 + (((quad + 4*ks) ^ sw) * 8)];
      #pragma unroll
      for (int mi = 0; mi < 4; ++mi)
        #pragma unroll
        for (int ni = 0; ni < FN; ++ni)
          acc[mi][ni] = __builtin_amdgcn_mfma_f32_16x16x32_bf16(aF[mi], bF[ni], acc[mi][ni], 0, 0, 0);
    }
    __syncthreads();
  }

  const int obf = (out_mode == 2) ? inbf : (out_mode == 0);
  #pragma unroll
  for (int ni = 0; ni < FN; ++ni) {
    int colg = col0 + wn_off + ni*16 + l15;
    if (colg >= Nn) continue;
    float bv = bias ? ldf(bias, colg, inbf) : 0.f;
    #pragma unroll
    for (int mi = 0; mi < 4; ++mi) {
      #pragma unroll
      for (int r = 0; r < 4; ++r) {
        int rowg = row0 + wm + mi*16 + quad*4 + r;
        int orow = rowg;
        if (omap) { int b = rowg >> 10, l = rowg & 1023; orow = (b << 10) + omap[l]; }
        float v = acc[mi][ni][r] + bv;
        if (out2 && colg < 64)
          out2[(size_t)orow * 64 + colg] = f2bf(colg < DR_ ? v : 0.f);
        if (act == 1)      v = (v > 20.f) ? v : log1pf(__expf(v));                  // softplus
        else if (act == 2) v = 0.5f * v * (1.f + erff(v * 0.70710678118654752f));   // gelu
        if (resid) v += ldf(resid, (size_t)orow * ldr + colg, inbf);
        size_t oi = (size_t)orow * ldo + colg;
        if (obf) ((ushort_t*)Out)[oi] = f2bf(v);
        else     ((float*)Out)[oi]    = v;
      }
    }
  }
}

// ---------------------------------------------------------------- conv(K=4)+silu
__global__ __launch_bounds__(256) void conv_silu_k(
    const ushort_t* __restrict__ u,
    const void* __restrict__ cw0, const void* __restrict__ cw1,
    const void* __restrict__ cb0, const void* __restrict__ cb1,
    ushort_t* __restrict__ uc, const int* __restrict__ flagp)
{
  const int inbf = *flagp;
  int g = blockIdx.x * 256 + threadIdx.x;
  int c = g % C_;
  int row = g / C_;
  int l = row & 1023;
  const void* cw = (row >> 12) ? cw1 : cw0;
  const void* cb = (row >> 12) ? cb1 : cb0;
  float w0 = ldf(cw, c*4+0, inbf), w1 = ldf(cw, c*4+1, inbf);
  float w2 = ldf(cw, c*4+2, inbf), w3 = ldf(cw, c*4+3, inbf);
  const ushort_t* up = u + (size_t)(row - l) * C_ + c;
  float s = ldf(cb, c, inbf);
  if (l >= 3) s += w0 * bf2f(up[(size_t)(l-3) * C_]);
  if (l >= 2) s += w1 * bf2f(up[(size_t)(l-2) * C_]);
  if (l >= 1) s += w2 * bf2f(up[(size_t)(l-1) * C_]);
  s += w3 * bf2f(up[(size_t)l * C_]);
  s = s / (1.f + __expf(-s));
  uc[g] = f2bf(s);
}

// ---------------------------------------------------------------- segmented scan
// State-parallel (4 lanes/channel, 4 states each) + LDS-staged operands.
// Round-3 lesson: state-parallel WITHOUT staging quadruples scalar VMEM and
// each wave load fetches 32 useful bytes -> slower. Fix: stage dt/uc (and B/C)
// tiles into LDS with coalesced global_load_lds (16B/lane), read per-l values
// from LDS (4-lane same-address = broadcast). pass3 also accumulates output in
// an f32 LDS tile and writes y via a fully-coalesced short8 epilogue.
// Rounds 7-9 lesson: SEG=32 (2x occupancy), 1-thread/channel (fewer ops), and
// grid-barrier fusion were all null or fatal; this structure is the floor.
__global__ __launch_bounds__(256) void scan_pass1(
    const ushort_t* __restrict__ dt, const ushort_t* __restrict__ uc,
    const float* __restrict__ dbl,
    const void* __restrict__ Alog_cw, const void* __restrict__ Alog_ccw,
    ushort_t* __restrict__ P, ushort_t* __restrict__ Q,
    const int* __restrict__ flagp)
{
  const int inbf = *flagp;
  const int db = blockIdx.z, d = db >> 2;
  const int s = blockIdx.y;
  const int tid = threadIdx.x;
  const int cl = tid >> 2;             // channel-local 0..63
  const int n4 = tid & 3;              // state group (4 states)
  const int c0 = blockIdx.x * 64;
  const int c = c0 + cl;
  const int l0 = s * SEG_;

  __shared__ __align__(16) float    BsS[SEG_ * 16];   // 4KB  [l][16] B cols
  __shared__ __align__(16) ushort_t dtS[SEG_ * 64];   // 8KB  [l][64]
  __shared__ __align__(16) ushort_t ucS[SEG_ * 64];   // 8KB
  {
    // B tile: 256 chunks x 16B (row l, 4 f32 per chunk)
    {
      int row = tid >> 2, col = (tid & 3) * 4;
      gload_lds16(dbl + ((size_t)db * L_ + l0 + row) * 80 + DR_ + col,
                  (char*)BsS + tid * 16);
    }
    // dt/uc tiles: 512 chunks x 16B each (row l, 8 bf16 per chunk)
    #pragma unroll
    for (int i = 0; i < 2; ++i) {
      int ch = i * 256 + tid;
      int row = ch >> 3, col = (ch & 7) * 8;
      size_t go = ((size_t)db * L_ + l0 + row) * C_ + c0 + col;
      gload_lds16(dt + go, (char*)dtS + ch * 16);
      gload_lds16(uc + go, (char*)ucS + ch * 16);
    }
  }
  __syncthreads();

  const void* Alog = d ? Alog_ccw : Alog_cw;
  float a[4];
  #pragma unroll
  for (int j = 0; j < 4; ++j) a[j] = -__expf(ldf(Alog, c * N_ + n4*4 + j, inbf));

  float h[4] = {0.f, 0.f, 0.f, 0.f};
  float S = 0.f;

  #pragma unroll 8
  for (int l = 0; l < SEG_; ++l) {
    float dtv = bf2f(dtS[l * 64 + cl]);
    float ucv = bf2f(ucS[l * 64 + cl]);
    float dtu = dtv * ucv;
    S += dtv;
    f32x4 bq = *(const f32x4*)&BsS[l * 16 + n4 * 4];
    #pragma unroll
    for (int j = 0; j < 4; ++j) { float dA = __expf(dtv*a[j]); h[j] = h[j]*dA + dtu*bq[j]; }
  }
  size_t idx = (((size_t)db * NSEG_ + s) * C_ + c) * N_ + n4*4;
  u16x4 pv, qv;
  #pragma unroll
  for (int j = 0; j < 4; ++j) { pv[j] = f2bf(__expf(a[j] * S)); qv[j] = f2bf(h[j]); }
  *(u16x4*)&P[idx] = pv;
  *(u16x4*)&Q[idx] = qv;
}

__global__ __launch_bounds__(256) void scan_pass2(
    ushort_t* __restrict__ P, ushort_t* __restrict__ Q)
{
  size_t g = (size_t)blockIdx.x * 256 + threadIdx.x;
  size_t db = g / (C_ * N_);
  size_t cn = g % (C_ * N_);
  float h = 0.f;
  #pragma unroll
  for (int s = 0; s < NSEG_; ++s) {
    size_t off = (db * NSEG_ + s) * (C_ * N_) + cn;
    float p = bf2f(P[off]), q = bf2f(Q[off]);
    Q[off] = f2bf(h);
    h = h * p + q;
  }
}

__global__ __launch_bounds__(256) void scan_pass3(
    const ushort_t* __restrict__ dt, const ushort_t* __restrict__ uc,
    const float* __restrict__ dbl, const ushort_t* __restrict__ z,
    const void* __restrict__ Alog_cw, const void* __restrict__ Alog_ccw,
    const void* __restrict__ D_cw, const void* __restrict__ D_ccw,
    const ushort_t* __restrict__ Q, ushort_t* __restrict__ y,
    const int* __restrict__ flagp)
{
  const int inbf = *flagp;
  const int db = blockIdx.z, d = db >> 2;
  const int s = blockIdx.y;
  const int tid = threadIdx.x;
  const int cl = tid >> 2;             // channel-local 0..63
  const int n4 = tid & 3;              // state group (4 states)
  const int c0 = blockIdx.x * 64;
  const int c = c0 + cl;
  const int l0 = s * SEG_;

  __shared__ __align__(16) float    BsS[SEG_ * 32];   // 8KB  [l][32] B|C cols
  __shared__ __align__(16) ushort_t dtS[SEG_ * 64];   // 8KB
  __shared__ __align__(16) ushort_t ucS[SEG_ * 64];   // 8KB
  __shared__ __align__(16) float    yS [SEG_ * 64];   // 16KB pre-silu output
  {
    // B|C tile: 512 chunks x 16B
    #pragma unroll
    for (int i = 0; i < 2; ++i) {
      int ch = i * 256 + tid;
      int row = ch >> 3, col = (ch & 7) * 4;
      gload_lds16(dbl + ((size_t)db * L_ + l0 + row) * 80 + DR_ + col,
                  (char*)BsS + ch * 16);
    }
    // dt/uc tiles: 512 chunks x 16B each
    #pragma unroll
    for (int i = 0; i < 2; ++i) {
      int ch = i * 256 + tid;
      int row = ch >> 3, col = (ch & 7) * 8;
      size_t go = ((size_t)db * L_ + l0 + row) * C_ + c0 + col;
      gload_lds16(dt + go, (char*)dtS + ch * 16);
      gload_lds16(uc + go, (char*)ucS + ch * 16);
    }
  }
  __syncthreads();

  const void* Alog = d ? Alog_ccw : Alog_cw;
  const void* Dp   = d ? D_ccw   : D_cw;
  float a[4];
  #pragma unroll
  for (int j = 0; j < 4; ++j) a[j] = -__expf(ldf(Alog, c * N_ + n4*4 + j, inbf));
  const float dvc = ldf(Dp, c, inbf);

  size_t idx = (((size_t)db * NSEG_ + s) * C_ + c) * N_ + n4*4;
  float h[4];
  #pragma unroll
  for (int j = 0; j < 4; ++j) h[j] = bf2f(Q[idx + j]);

  #pragma unroll 4
  for (int l = 0; l < SEG_; ++l) {
    float dtv = bf2f(dtS[l * 64 + cl]);
    float ucv = bf2f(ucS[l * 64 + cl]);
    float dtu = dtv * ucv;
    f32x4 bq = *(const f32x4*)&BsS[l * 32 + n4 * 4];
    f32x4 cq = *(const f32x4*)&BsS[l * 32 + 16 + n4 * 4];
    float yv = 0.f;
    #pragma unroll
    for (int j = 0; j < 4; ++j) { float dA = __expf(dtv*a[j]); h[j] = h[j]*dA + dtu*bq[j]; yv += h[j]*cq[j]; }
    // reduce partial yv across the 4 state-group lanes
    yv += __shfl_xor(yv, 1);
    yv += __shfl_xor(yv, 2);
    if (n4 == 0) yS[l * 64 + cl] = yv + dvc * ucv;
  }
  __syncthreads();

  // coalesced epilogue: o = yS * silu(z), short8 stores
  #pragma unroll
  for (int i = 0; i < 2; ++i) {
    int ch = i * 256 + tid;
    int row = ch >> 3, col = (ch & 7) * 8;
    size_t go = ((size_t)db * L_ + l0 + row) * C_ + c0 + col;
    short8 zr = *(const short8*)(z + go);
    f32x4 y0 = *(const f32x4*)&yS[row * 64 + col];
    f32x4 y1 = *(const f32x4*)&yS[row * 64 + col + 4];
    short8 res;
    #pragma unroll
    for (int j = 0; j < 4; ++j) {
      float zv = bf2f((ushort_t)zr[j]);
      res[j] = (short)f2bf(y0[j] * zv / (1.f + __expf(-zv)));
    }
    #pragma unroll
    for (int j = 0; j < 4; ++j) {
      float zv = bf2f((ushort_t)zr[4 + j]);
      res[4 + j] = (short)f2bf(y1[j] * zv / (1.f + __expf(-zv)));
    }
    *(short8*)(y + go) = res;
  }
}

// ---------------------------------------------------------------- launch
extern "C" void kernel_launch(void* const* d_in, const int* in_sizes, int n_in,
                              void* d_out, int out_size, void* d_ws, size_t ws_size,
                              hipStream_t stream)
{
  const void* x      = d_in[0];
  const void* norm_w = d_in[1];
  const void* norm_b = d_in[2];
  const void* in_w[2]    = { d_in[3],  d_in[12] };
  const void* conv_w[2]  = { d_in[4],  d_in[13] };
  const void* conv_b[2]  = { d_in[5],  d_in[14] };
  const void* xproj_w[2] = { d_in[6],  d_in[15] };
  const void* dtp_w[2]   = { d_in[7],  d_in[16] };
  const void* dtp_b[2]   = { d_in[8],  d_in[17] };
  const void* A_log[2]   = { d_in[9],  d_in[18] };
  const void* Dvec[2]    = { d_in[10], d_in[19] };
  const void* out_w[2]   = { d_in[11], d_in[20] };
  const void* fus_w1 = d_in[21];
  const void* fus_b1 = d_in[22];
  const void* fus_w2 = d_in[23];
  const void* fus_b2 = d_in[24];

  char* base = (char*)d_ws;
  int*      IDX  = (int*)base;
  int*      FLAG = (int*)(base + 8192);
  ushort_t* XN   = (ushort_t*)(base + 8448);
  ushort_t* U    = (ushort_t*)(base + 6299904);
  ushort_t* Z    = (ushort_t*)(base + 18882816);
  ushort_t* UC   = (ushort_t*)(base + 31465728);
  float*    DBL  = (float*)(base + 44048640);
  ushort_t* Y    = (ushort_t*)(base + 46670080);
  // lifetime aliases
  ushort_t* DT    = U;                                  // S5 out, scan in
  ushort_t* FUSED = Z;                                  // S7 out, S8 in
  ushort_t* HBUF  = XN;                                 // S8 out, S9 in
  ushort_t* SP = (ushort_t*)(base + 8448);              // scan only (bf16)
  ushort_t* SQ = SP + (size_t)2 * 4 * NSEG_ * C_ * N_;
  ushort_t* DTC = XN;                                   // S4 out2, S5 in
  ushort_t* INWT = UC;                                  // [2][1536][768], S2
  ushort_t* uout = (ushort_t*)d_out;
  ushort_t* XPJT = uout;                                // [2][128][768], S4
  ushort_t* DTPT = uout + 196608;                       // [2][768][64],  S5
  ushort_t* OWT  = uout + 294912;                       // [2][768][768], S7
  ushort_t* FW1T = U;                                   // [768][1536], S8
  ushort_t* FW2T = U + (size_t)768 * 1536;              // [768][768],  S9

  const size_t SD = (size_t)M_ * C_;

  // ---- prep: weight transposes + layernorm + spiral idx + FLAG, one dispatch
  {
    TJ tj; tj.njobs = 8;
    for (int d = 0; d < 2; ++d) {
      int j = d;
      tj.src[j]=in_w[d]; tj.dst[j]=INWT+(size_t)d*1536*768;
      tj.R[j]=768; tj.Cc[j]=1536; tj.RD[j]=1536; tj.ldD[j]=768;
    }
    for (int d = 0; d < 2; ++d) {
      int j = 2+d;
      tj.src[j]=xproj_w[d]; tj.dst[j]=XPJT+(size_t)d*128*768;
      tj.R[j]=768; tj.Cc[j]=80; tj.RD[j]=128; tj.ldD[j]=768;
    }
    for (int d = 0; d < 2; ++d) {
      int j = 4+d;
      tj.src[j]=dtp_w[d]; tj.dst[j]=DTPT+(size_t)d*768*64;
      tj.R[j]=48; tj.Cc[j]=768; tj.RD[j]=768; tj.ldD[j]=64;
    }
    for (int d = 0; d < 2; ++d) {
      int j = 6+d;
      tj.src[j]=out_w[d]; tj.dst[j]=OWT+(size_t)d*768*768;
      tj.R[j]=768; tj.Cc[j]=768; tj.RD[j]=768; tj.ldD[j]=768;
    }
    tj.off[0] = 0;
    for (int j = 0; j < 8; ++j) {
      int cspan = tj.Cc[j] > tj.RD[j] ? tj.Cc[j] : tj.RD[j];
      int rspan = tj.R[j] > tj.ldD[j] ? tj.R[j] : tj.ldD[j];
      tj.off[j+1] = tj.off[j] + ((cspan+31)>>5) * ((rspan+31)>>5);
    }
    int nblk = tj.off[8] + M_ + 1;
    hipLaunchKernelGGL(prep_k, dim3(nblk), dim3(256), 0, stream,
        tj, x, norm_w, norm_b, XN, IDX, IDX + L_, FLAG);
  }

  GB gb;
  for (int i = 0; i < 4; ++i) { gb.out2[i] = nullptr; gb.omap[i] = nullptr; gb.amap[i] = nullptr; gb.bias[i] = nullptr; }

  // ---- S2: in_proj, z = (d, u/z half), BM=64 BN=64, grid 12x64x4 = 3072
  for (int zz = 0; zz < 4; ++zz) {
    int d = zz >> 1, half = zz & 1;
    gb.A[zz] = XN; gb.amap[zz] = IDX + d * L_;
    gb.WT[zz] = INWT + (size_t)d*1536*768 + (size_t)half*768*768;
    gb.bias[zz] = nullptr;
    gb.out[zz] = (void*)((half ? Z : U) + d * SD); gb.out2[zz] = nullptr; gb.omap[zz] = nullptr;
  }
  hipLaunchKernelGGL((mgemm_k<64,64>), dim3(12, 64, 4), dim3(256), 0, stream,
      gb, C_, C_, C_, C_, C_, 0, 0, (const void*)nullptr, 0, FLAG);

  // ---- S3: conv + silu (both dirs, one dispatch)
  hipLaunchKernelGGL(conv_silu_k, dim3(2*M_*C_/256), dim3(256), 0, stream,
      U, conv_w[0], conv_w[1], conv_b[0], conv_b[1], UC, FLAG);

  // ---- S4: xproj -> DBL fp32 (+fused dtc), BM=64 BN=64, Nn=80, grid 2x64x2
  for (int zz = 0; zz < 2; ++zz) {
    gb.A[zz] = UC + zz * SD; gb.amap[zz] = nullptr;
    gb.WT[zz] = XPJT + (size_t)zz*128*768;
    gb.bias[zz] = nullptr;
    gb.out[zz] = (void*)(DBL + (size_t)zz * M_ * 80);
    gb.out2[zz] = DTC + (size_t)zz * M_ * 64;
    gb.omap[zz] = nullptr;
  }
  hipLaunchKernelGGL((mgemm_k<64,64>), dim3(2, 64, 2), dim3(256), 0, stream,
      gb, C_, C_, 80, C_, 80, 0, 1, (const void*)nullptr, 0, FLAG);

  // ---- S5: dt = softplus(dtc @ dtp_w + dtp_b), K=64, BM=64 BN=64, grid 12x64x2
  for (int zz = 0; zz < 2; ++zz) {
    gb.A[zz] = DTC + (size_t)zz * M_ * 64; gb.amap[zz] = nullptr;
    gb.WT[zz] = DTPT + (size_t)zz*768*64;
    gb.bias[zz] = dtp_b[zz];
    gb.out[zz] = (void*)(DT + zz * SD); gb.out2[zz] = nullptr; gb.omap[zz] = nullptr;
  }
  hipLaunchKernelGGL((mgemm_k<64,64>), dim3(12, 64, 2), dim3(256), 0, stream,
      gb, 64, 64, C_, 64, C_, 1, 0, (const void*)nullptr, 0, FLAG);

  // ---- S6: segmented selective scan (state-parallel + LDS-staged)
  hipLaunchKernelGGL(scan_pass1, dim3(12, NSEG_, 8), dim3(256), 0, stream,
      DT, UC, DBL, A_log[0], A_log[1], SP, SQ, FLAG);
  hipLaunchKernelGGL(scan_pass2, dim3(8 * C_ * N_ / 256), dim3(256), 0, stream, SP, SQ);
  hipLaunchKernelGGL(scan_pass3, dim3(3, NSEG_, 8), dim3(256), 0, stream,
      DT, UC, DBL, Z, A_log[0], A_log[1], Dvec[0], Dvec[1], SQ, Y, FLAG);

  // ---- batched transposes #2 (fus weights; U region free after scan)
  {
    TJ tj; tj.njobs = 2;
    tj.src[0]=fus_w1; tj.dst[0]=FW1T; tj.R[0]=1536; tj.Cc[0]=768; tj.RD[0]=768; tj.ldD[0]=1536;
    tj.src[1]=fus_w2; tj.dst[1]=FW2T; tj.R[1]=768;  tj.Cc[1]=768; tj.RD[1]=768; tj.ldD[1]=768;
    tj.off[0] = 0;
    for (int j = 0; j < 2; ++j) {
      int cspan = tj.Cc[j] > tj.RD[j] ? tj.Cc[j] : tj.RD[j];
      int rspan = tj.R[j] > tj.ldD[j] ? tj.R[j] : tj.ldD[j];
      tj.off[j+1] = tj.off[j] + ((cspan+31)>>5) * ((rspan+31)>>5);
    }
    hipLaunchKernelGGL(tbatch_k, dim3(tj.off[2]), dim3(256), 0, stream, tj, FLAG);
  }

  // ---- S7: out_proj with spiral-inverse scatter, BM=64 BN=64, grid 12x64x2
  for (int zz = 0; zz < 2; ++zz) {
    gb.A[zz] = Y + zz * SD; gb.amap[zz] = nullptr;
    gb.WT[zz] = OWT + (size_t)zz*768*768;
    gb.bias[zz] = nullptr;
    gb.out[zz] = (void*)(FUSED + zz * C_); gb.out2[zz] = nullptr; gb.omap[zz] = IDX + zz * L_;
  }
  hipLaunchKernelGGL((mgemm_k<64,64>), dim3(12, 64, 2), dim3(256), 0, stream,
      gb, C_, C_, C_, C_, 2*C_, 0, 0, (const void*)nullptr, 0, FLAG);

  // ---- S8: h = gelu(fused @ fus_w1 + fus_b1), K=1536, BM=64 BN=64, grid 12x64x1
  gb.A[0] = FUSED; gb.amap[0] = nullptr;
  gb.WT[0] = FW1T; gb.bias[0] = fus_b1;
  gb.out[0] = (void*)HBUF; gb.out2[0] = nullptr; gb.omap[0] = nullptr;
  hipLaunchKernelGGL((mgemm_k<64,64>), dim3(12, 64, 1), dim3(256), 0, stream,
      gb, 2*C_, 2*C_, C_, 2*C_, C_, 2, 0, (const void*)nullptr, 0, FLAG);

  // ---- S9: out = h @ fus_w2 + fus_b2 + x, BM=64 BN=64, grid 12x64x1
  gb.A[0] = HBUF; gb.amap[0] = nullptr;
  gb.WT[0] = FW2T; gb.bias[0] = fus_b2;
  gb.out[0] = d_out; gb.out2[0] = nullptr; gb.omap[0] = nullptr;
  hipLaunchKernelGGL((mgemm_k<64,64>), dim3(12, 64, 1), dim3(256), 0, stream,
      gb, C_, C_, C_, C_, C_, 0, 2, x, C_, FLAG);
}